// Round 12
// baseline (1166.206 us; speedup 1.0000x reference)
//
#include <hip/hip_runtime.h>
#include <hip/hip_bf16.h>
#include <stdint.h>

// Problem geometry (fixed by reference)
#define NQ 4096      // 64*8*8 query rows
#define NS 40960     // 32768 (s1) + 8192 (s_src)
#define CDIM 512
#define QT 128       // q rows per block: 4 waves x 32 q
#define SC 32        // s rows per chunk
#define NSPLIT 32    // s-dimension splits
#define SPER (NS / NSPLIT)   // 1280
#define NCHUNK (SPER / SC)   // 40
#define NCAND 960    // per-row candidates: 32 splits * 2 lane-halves * 15

typedef float f32x16 __attribute__((ext_vector_type(16)));
typedef unsigned int u32x4 __attribute__((ext_vector_type(4)));
typedef unsigned int u32x2 __attribute__((ext_vector_type(2)));

__device__ __forceinline__ unsigned short f2bf(float f) {
    uint32_t u = __builtin_bit_cast(uint32_t, f);
    u += 0x7fffu + ((u >> 16) & 1u);   // RNE (finite values only here)
    return (unsigned short)(u >> 16);
}
__device__ __forceinline__ float bf2f(unsigned short u) {
    uint32_t x = ((uint32_t)u) << 16;
    return __builtin_bit_cast(float, x);
}
// k-permutation baked into BOTH qn and sn fp8 layouts (dot-product invariant):
// swap bits 3,4 of the channel index so one 16B LDS slot holds the two 8B
// MFMA operands (m=2kk, 2kk+1) for a lane's k-half.
__device__ __forceinline__ int kperm(int c) {
    return (c & ~24) | ((c & 8) << 1) | ((c & 16) >> 1);
}

// CK-proven cast pattern: generic -> AS1/AS3 via uintptr
__device__ __forceinline__ void async_load16(const void* g, void* l) {
    auto gp = reinterpret_cast<const __attribute__((address_space(1))) uint32_t*>(
        reinterpret_cast<uintptr_t>(g));
    auto lp = reinterpret_cast<__attribute__((address_space(3))) uint32_t*>(
        reinterpret_cast<uintptr_t>(l));
    __builtin_amdgcn_global_load_lds(gp, lp, 16 /*bytes, literal*/, 0, 0);
}

// Branchless sorted-desc insert: r[i] = med3(v, r[i-1], r[i]) for i=14..1, then max.
__device__ __forceinline__ void ins15(float (&r)[15], float v) {
#pragma unroll
    for (int i = 14; i >= 1; --i) r[i] = __builtin_amdgcn_fmed3f(v, r[i - 1], r[i]);
    r[0] = fmaxf(r[0], v);
}

// ---------------- Phase A1: pool q (4x4 mean) + row-normalize -> fp8 (k-permuted) ----------------
__global__ __launch_bounds__(256) void pool_q_norm(const float* __restrict__ q,
                                                   char* __restrict__ qn) {
    int bb = blockIdx.x >> 3, h = blockIdx.x & 7;
    int t = threadIdx.x, lane = t & 63, wid = t >> 6;
    float vals[2][8];
    float ss[8] = {0, 0, 0, 0, 0, 0, 0, 0};
#pragma unroll
    for (int e = 0; e < 2; ++e) {
        int c = 2 * t + e;
        const float* base = q + ((size_t)(bb * 512 + c) * 1024 + 4 * h * 32);
#pragma unroll
        for (int w2 = 0; w2 < 8; ++w2) vals[e][w2] = 0.f;
#pragma unroll
        for (int i = 0; i < 4; ++i) {
            const float4* row = (const float4*)(base + i * 32);
#pragma unroll
            for (int w2 = 0; w2 < 8; ++w2) {
                float4 v = row[w2];
                vals[e][w2] += (v.x + v.y) + (v.z + v.w);
            }
        }
#pragma unroll
        for (int w2 = 0; w2 < 8; ++w2) {
            vals[e][w2] *= (1.f / 16.f);
            ss[w2] += vals[e][w2] * vals[e][w2];
        }
    }
    __shared__ float red[8][4];
#pragma unroll
    for (int k = 0; k < 8; ++k) {
        float v = ss[k];
#pragma unroll
        for (int o = 32; o > 0; o >>= 1) v += __shfl_xor(v, o, 64);
        if (lane == 0) red[k][wid] = v;
    }
    __syncthreads();
    int cp = kperm(2 * t);
#pragma unroll
    for (int w2 = 0; w2 < 8; ++w2) {
        float inv = rsqrtf(red[w2][0] + red[w2][1] + red[w2][2] + red[w2][3]);
        int p = __builtin_amdgcn_cvt_pk_fp8_f32(vals[0][w2] * inv, vals[1][w2] * inv, 0, false);
        *(unsigned short*)(qn + (size_t)(bb * 64 + h * 8 + w2) * 512 + cp) = (unsigned short)(p & 0xffff);
    }
}

// ------- Phase A2: pool S at BOTH scales + row-normalize -> fp8 (k-permuted) -------
__global__ __launch_bounds__(256) void pool_s_norm(const float* __restrict__ S,
                                                   char* __restrict__ sn) {
    int bb = blockIdx.x >> 3, h2 = blockIdx.x & 7;
    int t = threadIdx.x, lane = t & 63, wid = t >> 6;
    __shared__ unsigned short tile[40 * 512];   // 40KB raw-bf16 values
    __shared__ float rowsum[40];
#pragma unroll
    for (int e = 0; e < 2; ++e) {
        int c = 2 * t + e;
        const float* base = S + ((size_t)(bb * 512 + c) * 1024 + 4 * h2 * 32);
        float s1v[2][16];
#pragma unroll
        for (int j = 0; j < 2; ++j) {
            const float4* r0 = (const float4*)(base + (2 * j) * 32);
            const float4* r1 = (const float4*)(base + (2 * j + 1) * 32);
#pragma unroll
            for (int f = 0; f < 8; ++f) {
                float4 a = r0[f], b2 = r1[f];
                s1v[j][2 * f]     = (a.x + a.y + b2.x + b2.y) * 0.25f;
                s1v[j][2 * f + 1] = (a.z + a.w + b2.z + b2.w) * 0.25f;
            }
        }
#pragma unroll
        for (int j = 0; j < 2; ++j)
#pragma unroll
            for (int w1 = 0; w1 < 16; ++w1)
                tile[(j * 16 + w1) * 512 + c] = f2bf(s1v[j][w1]);
#pragma unroll
        for (int w2 = 0; w2 < 8; ++w2) {
            float src = (s1v[0][2 * w2] + s1v[0][2 * w2 + 1] +
                         s1v[1][2 * w2] + s1v[1][2 * w2 + 1]) * 0.25f;
            tile[(32 + w2) * 512 + c] = f2bf(src);
        }
    }
    __syncthreads();
    // Row sums-of-squares: wave wid owns rows 4k+wid; 64 lanes x 8 bf16 per row.
#pragma unroll
    for (int k = 0; k < 10; ++k) {
        int row = 4 * k + wid;
        u32x4 d = *(const u32x4*)(&tile[row * 512 + lane * 8]);
        float s = 0.f;
#pragma unroll
        for (int j = 0; j < 4; ++j) {
            float x0 = bf2f((unsigned short)(d[j] & 0xffffu));
            float x1 = bf2f((unsigned short)(d[j] >> 16));
            s += x0 * x0 + x1 * x1;
        }
#pragma unroll
        for (int o = 32; o > 0; o >>= 1) s += __shfl_xor(s, o, 64);
        if (lane == 0) rowsum[row] = s;
    }
    __syncthreads();
    // Scale + fp8 cast + k-permuted coalesced 8B stores: 40 rows x 64 segs.
#pragma unroll
    for (int k = 0; k < 10; ++k) {
        int idx = t + 256 * k;
        int r = idx >> 6, seg = idx & 63;
        float inv = rsqrtf(rowsum[r]);
        const unsigned short* src = &tile[r * 512 + seg * 8];
        float x[8];
#pragma unroll
        for (int m = 0; m < 8; ++m) x[m] = bf2f(src[m]) * inv;
        unsigned int w0 = (unsigned int)__builtin_amdgcn_cvt_pk_fp8_f32(
            x[2], x[3], __builtin_amdgcn_cvt_pk_fp8_f32(x[0], x[1], 0, false), true);
        unsigned int w1 = (unsigned int)__builtin_amdgcn_cvt_pk_fp8_f32(
            x[6], x[7], __builtin_amdgcn_cvt_pk_fp8_f32(x[4], x[5], 0, false), true);
        int nseg = (seg & ~3) | ((seg & 1) << 1) | ((seg >> 1) & 1);   // swap k-bits 3,4
        int grow = (r < 32) ? (bb * 256 + (2 * h2 + (r >> 4)) * 16 + (r & 15))
                            : (32768 + bb * 64 + h2 * 8 + (r - 32));
        uint2 o2; o2.x = w0; o2.y = w1;
        *(uint2*)(sn + (size_t)grow * 512 + nseg * 8) = o2;
    }
}

// ---------------- Phase B: fp8 32x32x16 MFMA + pipelined in-register top-15 ----------------
// 1024 blocks x 256 threads (4 waves x 32 q), 4 blocks/CU. XCD-pinned splits.
// KEY CHANGE vs R11: chunk-pair software pipeline — the per-kk MFMA loop body also
// inserts ONE element of the PREVIOUS chunk's acc into the top-15 list, so the
// scan VALU issues inside the 64-cyc MFMA pipe shadow (R11 measured the phases
// fully serialized: 75 MFMA + 98 VALU + 42 LDS ≈ 208 dur).
// accA/accB ping-pong with static names (rule #20); prev-acc starts at -2 so the
// first dummy scan is harmless; epilogue scans the final chunk.
__global__ __launch_bounds__(256, 4) void sim_topk(const char* __restrict__ qn,
                                                   const char* __restrict__ sn,
                                                   float* __restrict__ partial) {
    __shared__ char Bs[2][SC * 512];   // 2 x 16KB
    int id = blockIdx.x;
    int xcd = id & 7, j = id >> 3;     // j = 0..127
    int y = xcd * 4 + (j & 3);         // s-split 0..31, pinned to XCD
    int x = j >> 2;                    // q-tile 0..31
    int tid = threadIdx.x, lane = tid & 63, wid = tid >> 6;
    int rlo = lane & 31, hi = lane >> 5;
    int qbase = x * QT + wid * 32;
    int sbase = y * SPER;
    char* BsB = &Bs[0][0];

    // B fragments (q side, fp8): 32 q rows, full K=512 (k-permuted layout).
    u32x4 b[16];
    {
        const char* qp = qn + (size_t)(qbase + rlo) * 512 + hi * 16;
#pragma unroll
        for (int kk = 0; kk < 16; ++kk) b[kk] = *(const u32x4*)(qp + kk * 32);
    }

    float r0[15];
#pragma unroll
    for (int i = 0; i < 15; ++i) r0[i] = -2.0f;   // below min cosine

    auto stage = [&](int ch, int buf) {
#pragma unroll
        for (int ii = 0; ii < 4; ++ii) {
            int i = wid * 4 + ii;                 // wave-uniform instr idx, 2 rows each
            int row = 2 * i + hi;                 // 0..31
            size_t srcoff = (size_t)(sbase + ch * SC + row) * 512
                          + (size_t)((rlo ^ row) * 16);
            async_load16(sn + srcoff, BsB + buf * 16384 + i * 1024);
        }
    };

    stage(0, 0);
    stage(1, 1);
    f32x16 accAE, accAO, accBE, accBO;
#pragma unroll
    for (int e = 0; e < 16; ++e) { accBE[e] = -2.0f; accBO[e] = 0.f; }  // sum = -2

    for (int it = 0; it < NCHUNK / 2; ++it) {
        int ch = 2 * it;
        // ---- even phase: MFMA chunk ch (buf0) -> accA; scan accB (chunk ch-1) ----
        asm volatile("s_waitcnt vmcnt(4)" ::: "memory");   // chunk ch's loads landed
        __builtin_amdgcn_s_barrier();
#pragma unroll
        for (int kk = 0; kk < 16; ++kk) asm volatile("" : "+v"(b[kk]));
#pragma unroll
        for (int e = 0; e < 16; ++e) { accAE[e] = 0.f; accAO[e] = 0.f; }
#pragma unroll
        for (int kk = 0; kk < 16; ++kk) {
            int slot = ((kk * 2 + hi) ^ rlo) * 16;
            u32x4 aA = *(const u32x4*)(BsB + rlo * 512 + slot);
            long aAlo = __builtin_bit_cast(long, (u32x2){aA[0], aA[1]});
            long aAhi = __builtin_bit_cast(long, (u32x2){aA[2], aA[3]});
            long blo = __builtin_bit_cast(long, (u32x2){b[kk][0], b[kk][1]});
            long bhi = __builtin_bit_cast(long, (u32x2){b[kk][2], b[kk][3]});
            accAE = __builtin_amdgcn_mfma_f32_32x32x16_fp8_fp8(aAlo, blo, accAE, 0, 0, 0);
            accAO = __builtin_amdgcn_mfma_f32_32x32x16_fp8_fp8(aAhi, bhi, accAO, 0, 0, 0);
            ins15(r0, accBE[kk] + accBO[kk]);   // scan prev chunk in MFMA shadow
        }
        __builtin_amdgcn_s_barrier();   // buf0 reads retired
        { int n = ch + 2; if (n >= NCHUNK) n -= NCHUNK; stage(n, 0); }

        // ---- odd phase: MFMA chunk ch+1 (buf1) -> accB; scan accA (chunk ch) ----
        asm volatile("s_waitcnt vmcnt(4)" ::: "memory");
        __builtin_amdgcn_s_barrier();
#pragma unroll
        for (int kk = 0; kk < 16; ++kk) {
            int slot = ((kk * 2 + hi) ^ rlo) * 16;
            u32x4 aA = *(const u32x4*)(BsB + 16384 + rlo * 512 + slot);
            long aAlo = __builtin_bit_cast(long, (u32x2){aA[0], aA[1]});
            long aAhi = __builtin_bit_cast(long, (u32x2){aA[2], aA[3]});
            long blo = __builtin_bit_cast(long, (u32x2){b[kk][0], b[kk][1]});
            long bhi = __builtin_bit_cast(long, (u32x2){b[kk][2], b[kk][3]});
            f32x16 tE = (kk == 0) ? (f32x16){0.f} : accBE;
            f32x16 tO = (kk == 0) ? (f32x16){0.f} : accBO;
            accBE = __builtin_amdgcn_mfma_f32_32x32x16_fp8_fp8(aAlo, blo, tE, 0, 0, 0);
            accBO = __builtin_amdgcn_mfma_f32_32x32x16_fp8_fp8(aAhi, bhi, tO, 0, 0, 0);
            ins15(r0, accAE[kk] + accAO[kk]);   // scan chunk ch in MFMA shadow
        }
        __builtin_amdgcn_s_barrier();   // buf1 reads retired
        { int n = ch + 3; if (n >= NCHUNK) n -= NCHUNK; stage(n, 1); }
    }
    // epilogue: scan the last chunk's acc (chunk NCHUNK-1)
#pragma unroll
    for (int e = 0; e < 16; ++e) ins15(r0, accBE[e] + accBO[e]);

    // Emit: partial[qrow][split][sub][15], sub = hi (s-row half within chunk rows)
    int q0 = qbase + rlo;
    float* dst = partial + (((size_t)q0 * NSPLIT + y) * 2 + hi) * 15;
#pragma unroll
    for (int i = 0; i < 15; ++i) dst[i] = r0[i];
}

// ---------------- Final: merge 960 candidates/row -> top15 -> LSE/top4 loss ----------------
// Wave per row, 4 rows/block, no per-round barriers, one atomicAdd per block.
__global__ __launch_bounds__(256) void topk_loss(const float* __restrict__ partial,
                                                 float* __restrict__ accum) {
    int t = threadIdx.x, lane = t & 63, wid = t >> 6;
    int r = blockIdx.x * 4 + wid;
    const float* src = partial + (size_t)r * NCAND;
    float v[15];
#pragma unroll
    for (int i = 0; i < 15; ++i) v[i] = src[lane + 64 * i];
    float m0 = 0.f, sexp = 0.f, top4 = 0.f;
#pragma unroll
    for (int round = 0; round < 15; ++round) {
        float m = v[0];
        int mi = lane * 16;
#pragma unroll
        for (int i = 1; i < 15; ++i)
            if (v[i] > m) { m = v[i]; mi = lane * 16 + i; }
#pragma unroll
        for (int o = 32; o > 0; o >>= 1) {
            float om = __shfl_xor(m, o, 64);
            int oi = __shfl_xor(mi, o, 64);
            if (om > m || (om == m && oi < mi)) { m = om; mi = oi; }
        }
        int wl = mi >> 4, wi = mi & 15;
#pragma unroll
        for (int i = 0; i < 15; ++i)
            if (i == wi && wl == lane) v[i] = -1e30f;   // static-index clear
        if (round == 0) m0 = m;
        sexp += expf(m - m0);
        if (round < 4) top4 += m;
    }
    float loss = m0 + logf(sexp) - 0.25f * top4;
    __shared__ float red[4];
    if (lane == 0) red[wid] = loss;
    __syncthreads();
    if (t == 0) atomicAdd(accum, red[0] + red[1] + red[2] + red[3]);
}

__global__ void finalize_out(const float* __restrict__ accum, float* __restrict__ out) {
    out[0] = accum[0] * (1.0f / (float)NQ);
}

// ---------------- Launch ----------------
extern "C" void kernel_launch(void* const* d_in, const int* in_sizes, int n_in,
                              void* d_out, int out_size, void* d_ws, size_t ws_size,
                              hipStream_t stream) {
    (void)in_sizes; (void)n_in; (void)out_size; (void)ws_size;
    const float* q = (const float*)d_in[0];
    const float* S = (const float*)d_in[1];
    char* ws = (char*)d_ws;
    char* qn = ws;                                                   //  2,097,152 B
    char* sn = ws + 2097152;                                         // 20,971,520 B
    float* partial = (float*)(ws + 2097152 + 20971520);              // 15,728,640 B
    float* accum   = (float*)(ws + 2097152 + 20971520 + 15728640);   // 4 B

    hipMemsetAsync(accum, 0, 4, stream);
    pool_q_norm<<<512, 256, 0, stream>>>(q, qn);
    pool_s_norm<<<1024, 256, 0, stream>>>(S, sn);
    sim_topk<<<1024, 256, 0, stream>>>(qn, sn, partial);
    topk_loss<<<NQ / 4, 256, 0, stream>>>(partial, accum);
    finalize_out<<<1, 1, 0, stream>>>(accum, (float*)d_out);
}

// Round 13
// 286.070 us; speedup vs baseline: 4.0766x; 4.0766x over previous
//
#include <hip/hip_runtime.h>
#include <hip/hip_bf16.h>
#include <stdint.h>

// Problem geometry (fixed by reference)
#define NQ 4096      // 64*8*8 query rows
#define NS 40960     // 32768 (s1) + 8192 (s_src)
#define CDIM 512
#define QT 128       // q rows per block: 4 waves x 32 q
#define SC 32        // s rows per chunk
#define NSPLIT 32    // s-dimension splits
#define SPER (NS / NSPLIT)   // 1280
#define NCHUNK (SPER / SC)   // 40
#define NCAND 960    // per-row candidates: 32 splits * 2 lane-halves * 15

typedef float f32x16 __attribute__((ext_vector_type(16)));
typedef unsigned int u32x4 __attribute__((ext_vector_type(4)));
typedef unsigned int u32x2 __attribute__((ext_vector_type(2)));

__device__ __forceinline__ unsigned short f2bf(float f) {
    uint32_t u = __builtin_bit_cast(uint32_t, f);
    u += 0x7fffu + ((u >> 16) & 1u);   // RNE (finite values only here)
    return (unsigned short)(u >> 16);
}
__device__ __forceinline__ float bf2f(unsigned short u) {
    uint32_t x = ((uint32_t)u) << 16;
    return __builtin_bit_cast(float, x);
}
// k-permutation baked into BOTH qn and sn fp8 layouts (dot-product invariant):
// swap bits 3,4 of the channel index so one 16B LDS slot holds the two 8B
// MFMA operands (m=2kk, 2kk+1) for a lane's k-half.
__device__ __forceinline__ int kperm(int c) {
    return (c & ~24) | ((c & 8) << 1) | ((c & 16) >> 1);
}

// CK-proven cast pattern: generic -> AS1/AS3 via uintptr
__device__ __forceinline__ void async_load16(const void* g, void* l) {
    auto gp = reinterpret_cast<const __attribute__((address_space(1))) uint32_t*>(
        reinterpret_cast<uintptr_t>(g));
    auto lp = reinterpret_cast<__attribute__((address_space(3))) uint32_t*>(
        reinterpret_cast<uintptr_t>(l));
    __builtin_amdgcn_global_load_lds(gp, lp, 16 /*bytes, literal*/, 0, 0);
}

// Branchless sorted-desc insert: r[i] = med3(v, r[i-1], r[i]) for i=14..1, then max.
__device__ __forceinline__ void ins15(float (&r)[15], float v) {
#pragma unroll
    for (int i = 14; i >= 1; --i) r[i] = __builtin_amdgcn_fmed3f(v, r[i - 1], r[i]);
    r[0] = fmaxf(r[0], v);
}

// ---------------- Phase A1: pool q (4x4 mean) + row-normalize -> fp8 (k-permuted) ----------------
__global__ __launch_bounds__(256) void pool_q_norm(const float* __restrict__ q,
                                                   char* __restrict__ qn) {
    int bb = blockIdx.x >> 3, h = blockIdx.x & 7;
    int t = threadIdx.x, lane = t & 63, wid = t >> 6;
    float vals[2][8];
    float ss[8] = {0, 0, 0, 0, 0, 0, 0, 0};
#pragma unroll
    for (int e = 0; e < 2; ++e) {
        int c = 2 * t + e;
        const float* base = q + ((size_t)(bb * 512 + c) * 1024 + 4 * h * 32);
#pragma unroll
        for (int w2 = 0; w2 < 8; ++w2) vals[e][w2] = 0.f;
#pragma unroll
        for (int i = 0; i < 4; ++i) {
            const float4* row = (const float4*)(base + i * 32);
#pragma unroll
            for (int w2 = 0; w2 < 8; ++w2) {
                float4 v = row[w2];
                vals[e][w2] += (v.x + v.y) + (v.z + v.w);
            }
        }
#pragma unroll
        for (int w2 = 0; w2 < 8; ++w2) {
            vals[e][w2] *= (1.f / 16.f);
            ss[w2] += vals[e][w2] * vals[e][w2];
        }
    }
    __shared__ float red[8][4];
#pragma unroll
    for (int k = 0; k < 8; ++k) {
        float v = ss[k];
#pragma unroll
        for (int o = 32; o > 0; o >>= 1) v += __shfl_xor(v, o, 64);
        if (lane == 0) red[k][wid] = v;
    }
    __syncthreads();
    int cp = kperm(2 * t);
#pragma unroll
    for (int w2 = 0; w2 < 8; ++w2) {
        float inv = rsqrtf(red[w2][0] + red[w2][1] + red[w2][2] + red[w2][3]);
        int p = __builtin_amdgcn_cvt_pk_fp8_f32(vals[0][w2] * inv, vals[1][w2] * inv, 0, false);
        *(unsigned short*)(qn + (size_t)(bb * 64 + h * 8 + w2) * 512 + cp) = (unsigned short)(p & 0xffff);
    }
}

// ------- Phase A2: pool S at BOTH scales + row-normalize -> fp8 (k-permuted) -------
__global__ __launch_bounds__(256) void pool_s_norm(const float* __restrict__ S,
                                                   char* __restrict__ sn) {
    int bb = blockIdx.x >> 3, h2 = blockIdx.x & 7;
    int t = threadIdx.x, lane = t & 63, wid = t >> 6;
    __shared__ unsigned short tile[40 * 512];   // 40KB raw-bf16 values
    __shared__ float rowsum[40];
#pragma unroll
    for (int e = 0; e < 2; ++e) {
        int c = 2 * t + e;
        const float* base = S + ((size_t)(bb * 512 + c) * 1024 + 4 * h2 * 32);
        float s1v[2][16];
#pragma unroll
        for (int j = 0; j < 2; ++j) {
            const float4* r0 = (const float4*)(base + (2 * j) * 32);
            const float4* r1 = (const float4*)(base + (2 * j + 1) * 32);
#pragma unroll
            for (int f = 0; f < 8; ++f) {
                float4 a = r0[f], b2 = r1[f];
                s1v[j][2 * f]     = (a.x + a.y + b2.x + b2.y) * 0.25f;
                s1v[j][2 * f + 1] = (a.z + a.w + b2.z + b2.w) * 0.25f;
            }
        }
#pragma unroll
        for (int j = 0; j < 2; ++j)
#pragma unroll
            for (int w1 = 0; w1 < 16; ++w1)
                tile[(j * 16 + w1) * 512 + c] = f2bf(s1v[j][w1]);
#pragma unroll
        for (int w2 = 0; w2 < 8; ++w2) {
            float src = (s1v[0][2 * w2] + s1v[0][2 * w2 + 1] +
                         s1v[1][2 * w2] + s1v[1][2 * w2 + 1]) * 0.25f;
            tile[(32 + w2) * 512 + c] = f2bf(src);
        }
    }
    __syncthreads();
    // Row sums-of-squares: wave wid owns rows 4k+wid; 64 lanes x 8 bf16 per row.
#pragma unroll
    for (int k = 0; k < 10; ++k) {
        int row = 4 * k + wid;
        u32x4 d = *(const u32x4*)(&tile[row * 512 + lane * 8]);
        float s = 0.f;
#pragma unroll
        for (int j = 0; j < 4; ++j) {
            float x0 = bf2f((unsigned short)(d[j] & 0xffffu));
            float x1 = bf2f((unsigned short)(d[j] >> 16));
            s += x0 * x0 + x1 * x1;
        }
#pragma unroll
        for (int o = 32; o > 0; o >>= 1) s += __shfl_xor(s, o, 64);
        if (lane == 0) rowsum[row] = s;
    }
    __syncthreads();
    // Scale + fp8 cast + k-permuted coalesced 8B stores: 40 rows x 64 segs.
#pragma unroll
    for (int k = 0; k < 10; ++k) {
        int idx = t + 256 * k;
        int r = idx >> 6, seg = idx & 63;
        float inv = rsqrtf(rowsum[r]);
        const unsigned short* src = &tile[r * 512 + seg * 8];
        float x[8];
#pragma unroll
        for (int m = 0; m < 8; ++m) x[m] = bf2f(src[m]) * inv;
        unsigned int w0 = (unsigned int)__builtin_amdgcn_cvt_pk_fp8_f32(
            x[2], x[3], __builtin_amdgcn_cvt_pk_fp8_f32(x[0], x[1], 0, false), true);
        unsigned int w1 = (unsigned int)__builtin_amdgcn_cvt_pk_fp8_f32(
            x[6], x[7], __builtin_amdgcn_cvt_pk_fp8_f32(x[4], x[5], 0, false), true);
        int nseg = (seg & ~3) | ((seg & 1) << 1) | ((seg >> 1) & 1);   // swap k-bits 3,4
        int grow = (r < 32) ? (bb * 256 + (2 * h2 + (r >> 4)) * 16 + (r & 15))
                            : (32768 + bb * 64 + h2 * 8 + (r - 32));
        uint2 o2; o2.x = w0; o2.y = w1;
        *(uint2*)(sn + (size_t)grow * 512 + nseg * 8) = o2;
    }
}

// ---------------- Phase B: fp8 32x32x16 MFMA + pipelined in-register top-15 ----------------
// 1024 blocks x 256 threads (4 waves x 32 q), launch_bounds(256,2) -> VGPR cap 256
// (R12's spill root cause: cap 128 with 4 live f32x16 accs). 2 blocks/CU, 2 rounds.
// TRIPLE-buffered LDS (3x16KB) -> ONE barrier per chunk:
//   phase n: vmcnt(4) [my chunk-n loads done; 4 newest = chunk n+1]
//            s_barrier [all waves' chunk-n loads published; phase n-1 readers done]
//            stage(n+2) into buf (n+2)%3 [= buffer read at phase n-1, now free]
//            MFMA chunk n from buf n%3, with prev-chunk scan interleaved per-kk
// Scan-in-shadow: ins15(r0, sumPrev[kk]) sits in the 32-MFMA issue shadow; prev acc
// pre-summed to ONE f32x16 (peak live: b[16]=64 + 2 acc + 2 sum + r0 ~ 150 regs).
__global__ __launch_bounds__(256, 2) void sim_topk(const char* __restrict__ qn,
                                                   const char* __restrict__ sn,
                                                   float* __restrict__ partial) {
    __shared__ char Bs[3][SC * 512];   // 3 x 16KB
    int id = blockIdx.x;
    int xcd = id & 7, j = id >> 3;     // j = 0..127
    int y = xcd * 4 + (j & 3);         // s-split 0..31, pinned to XCD
    int x = j >> 2;                    // q-tile 0..31
    int tid = threadIdx.x, lane = tid & 63, wid = tid >> 6;
    int rlo = lane & 31, hi = lane >> 5;
    int qbase = x * QT + wid * 32;
    int sbase = y * SPER;
    char* BsB = &Bs[0][0];

    // B fragments (q side, fp8): 32 q rows, full K=512 (k-permuted layout).
    u32x4 b[16];
    {
        const char* qp = qn + (size_t)(qbase + rlo) * 512 + hi * 16;
#pragma unroll
        for (int kk = 0; kk < 16; ++kk) b[kk] = *(const u32x4*)(qp + kk * 32);
    }

    float r0[15];
#pragma unroll
    for (int i = 0; i < 15; ++i) r0[i] = -2.0f;   // below min cosine

    auto stage = [&](int ch, int buf) {
#pragma unroll
        for (int ii = 0; ii < 4; ++ii) {
            int i = wid * 4 + ii;                 // wave-uniform instr idx, 2 rows each
            int row = 2 * i + hi;                 // 0..31
            size_t srcoff = (size_t)(sbase + ch * SC + row) * 512
                          + (size_t)((rlo ^ row) * 16);
            async_load16(sn + srcoff, BsB + buf * 16384 + i * 1024);
        }
    };

    stage(0, 0);
    stage(1, 1);
    f32x16 sumP;                       // prev chunk's summed acc (scanned in shadow)
#pragma unroll
    for (int e = 0; e < 16; ++e) sumP[e] = -2.0f;
    int bufR = 0;   // buffer holding current chunk
    int bufS = 2;   // buffer to stage into
    int chS = 2;    // chunk to stage

    for (int it = 0; it < NCHUNK / 2; ++it) {
        // ---- even phase: MFMA chunk 2it; scan sumP (chunk 2it-1) ----
        asm volatile("s_waitcnt vmcnt(4)" ::: "memory");
        __builtin_amdgcn_s_barrier();
        stage(chS, bufS);
        chS = (chS + 1 == NCHUNK) ? 0 : chS + 1;
        bufS = (bufS + 1 == 3) ? 0 : bufS + 1;
#pragma unroll
        for (int kk = 0; kk < 16; ++kk) asm volatile("" : "+v"(b[kk]));
        const char* B0 = BsB + bufR * 16384;
        bufR = (bufR + 1 == 3) ? 0 : bufR + 1;
        f32x16 aE, aO;
#pragma unroll
        for (int e = 0; e < 16; ++e) { aE[e] = 0.f; aO[e] = 0.f; }
#pragma unroll
        for (int kk = 0; kk < 16; ++kk) {
            int slot = ((kk * 2 + hi) ^ rlo) * 16;
            u32x4 aA = *(const u32x4*)(B0 + rlo * 512 + slot);
            long aAlo = __builtin_bit_cast(long, (u32x2){aA[0], aA[1]});
            long aAhi = __builtin_bit_cast(long, (u32x2){aA[2], aA[3]});
            long blo = __builtin_bit_cast(long, (u32x2){b[kk][0], b[kk][1]});
            long bhi = __builtin_bit_cast(long, (u32x2){b[kk][2], b[kk][3]});
            aE = __builtin_amdgcn_mfma_f32_32x32x16_fp8_fp8(aAlo, blo, aE, 0, 0, 0);
            aO = __builtin_amdgcn_mfma_f32_32x32x16_fp8_fp8(aAhi, bhi, aO, 0, 0, 0);
            ins15(r0, sumP[kk]);               // prev-chunk scan in MFMA shadow
        }
        f32x16 sumA;
#pragma unroll
        for (int e = 0; e < 16; ++e) sumA[e] = aE[e] + aO[e];

        // ---- odd phase: MFMA chunk 2it+1; scan sumA (chunk 2it) ----
        asm volatile("s_waitcnt vmcnt(4)" ::: "memory");
        __builtin_amdgcn_s_barrier();
        stage(chS, bufS);
        chS = (chS + 1 == NCHUNK) ? 0 : chS + 1;
        bufS = (bufS + 1 == 3) ? 0 : bufS + 1;
        const char* B1 = BsB + bufR * 16384;
        bufR = (bufR + 1 == 3) ? 0 : bufR + 1;
        f32x16 bE, bO;
#pragma unroll
        for (int e = 0; e < 16; ++e) { bE[e] = 0.f; bO[e] = 0.f; }
#pragma unroll
        for (int kk = 0; kk < 16; ++kk) {
            int slot = ((kk * 2 + hi) ^ rlo) * 16;
            u32x4 aA = *(const u32x4*)(B1 + rlo * 512 + slot);
            long aAlo = __builtin_bit_cast(long, (u32x2){aA[0], aA[1]});
            long aAhi = __builtin_bit_cast(long, (u32x2){aA[2], aA[3]});
            long blo = __builtin_bit_cast(long, (u32x2){b[kk][0], b[kk][1]});
            long bhi = __builtin_bit_cast(long, (u32x2){b[kk][2], b[kk][3]});
            bE = __builtin_amdgcn_mfma_f32_32x32x16_fp8_fp8(aAlo, blo, bE, 0, 0, 0);
            bO = __builtin_amdgcn_mfma_f32_32x32x16_fp8_fp8(aAhi, bhi, bO, 0, 0, 0);
            ins15(r0, sumA[kk]);               // chunk-2it scan in MFMA shadow
        }
#pragma unroll
        for (int e = 0; e < 16; ++e) sumP[e] = bE[e] + bO[e];
    }
    // epilogue: scan the final chunk
#pragma unroll
    for (int e = 0; e < 16; ++e) ins15(r0, sumP[e]);

    // Emit: partial[qrow][split][sub][15], sub = hi (s-row half within chunk rows)
    int q0 = qbase + rlo;
    float* dst = partial + (((size_t)q0 * NSPLIT + y) * 2 + hi) * 15;
#pragma unroll
    for (int i = 0; i < 15; ++i) dst[i] = r0[i];
}

// ---------------- Final: merge 960 candidates/row -> top15 -> LSE/top4 loss ----------------
// Wave per row, 4 rows/block, no per-round barriers, one atomicAdd per block.
__global__ __launch_bounds__(256) void topk_loss(const float* __restrict__ partial,
                                                 float* __restrict__ accum) {
    int t = threadIdx.x, lane = t & 63, wid = t >> 6;
    int r = blockIdx.x * 4 + wid;
    const float* src = partial + (size_t)r * NCAND;
    float v[15];
#pragma unroll
    for (int i = 0; i < 15; ++i) v[i] = src[lane + 64 * i];
    float m0 = 0.f, sexp = 0.f, top4 = 0.f;
#pragma unroll
    for (int round = 0; round < 15; ++round) {
        float m = v[0];
        int mi = lane * 16;
#pragma unroll
        for (int i = 1; i < 15; ++i)
            if (v[i] > m) { m = v[i]; mi = lane * 16 + i; }
#pragma unroll
        for (int o = 32; o > 0; o >>= 1) {
            float om = __shfl_xor(m, o, 64);
            int oi = __shfl_xor(mi, o, 64);
            if (om > m || (om == m && oi < mi)) { m = om; mi = oi; }
        }
        int wl = mi >> 4, wi = mi & 15;
#pragma unroll
        for (int i = 0; i < 15; ++i)
            if (i == wi && wl == lane) v[i] = -1e30f;   // static-index clear
        if (round == 0) m0 = m;
        sexp += expf(m - m0);
        if (round < 4) top4 += m;
    }
    float loss = m0 + logf(sexp) - 0.25f * top4;
    __shared__ float red[4];
    if (lane == 0) red[wid] = loss;
    __syncthreads();
    if (t == 0) atomicAdd(accum, red[0] + red[1] + red[2] + red[3]);
}

__global__ void finalize_out(const float* __restrict__ accum, float* __restrict__ out) {
    out[0] = accum[0] * (1.0f / (float)NQ);
}

// ---------------- Launch ----------------
extern "C" void kernel_launch(void* const* d_in, const int* in_sizes, int n_in,
                              void* d_out, int out_size, void* d_ws, size_t ws_size,
                              hipStream_t stream) {
    (void)in_sizes; (void)n_in; (void)out_size; (void)ws_size;
    const float* q = (const float*)d_in[0];
    const float* S = (const float*)d_in[1];
    char* ws = (char*)d_ws;
    char* qn = ws;                                                   //  2,097,152 B
    char* sn = ws + 2097152;                                         // 20,971,520 B
    float* partial = (float*)(ws + 2097152 + 20971520);              // 15,728,640 B
    float* accum   = (float*)(ws + 2097152 + 20971520 + 15728640);   // 4 B

    hipMemsetAsync(accum, 0, 4, stream);
    pool_q_norm<<<512, 256, 0, stream>>>(q, qn);
    pool_s_norm<<<1024, 256, 0, stream>>>(S, sn);
    sim_topk<<<1024, 256, 0, stream>>>(qn, sn, partial);
    topk_loss<<<NQ / 4, 256, 0, stream>>>(partial, accum);
    finalize_out<<<1, 1, 0, stream>>>(accum, (float*)d_out);
}

// Round 14
// 268.710 us; speedup vs baseline: 4.3400x; 1.0646x over previous
//
#include <hip/hip_runtime.h>
#include <hip/hip_bf16.h>
#include <stdint.h>

// Problem geometry (fixed by reference)
#define NQ 4096      // 64*8*8 query rows
#define NS 40960     // 32768 (s1) + 8192 (s_src)
#define CDIM 512
#define QT 128       // q rows per block: 4 waves x 32 q
#define SC 32        // s rows per chunk
#define NSPLIT 32    // s-dimension splits
#define SPER (NS / NSPLIT)   // 1280
#define NCHUNK (SPER / SC)   // 40
#define NCAND 960    // per-row candidates: 32 splits * 2 lane-halves * 15

typedef float f32x16 __attribute__((ext_vector_type(16)));
typedef unsigned int u32x4 __attribute__((ext_vector_type(4)));
typedef int i32x4 __attribute__((ext_vector_type(4)));
typedef int i32x8 __attribute__((ext_vector_type(8)));

__device__ __forceinline__ unsigned short f2bf(float f) {
    uint32_t u = __builtin_bit_cast(uint32_t, f);
    u += 0x7fffu + ((u >> 16) & 1u);   // RNE (finite values only here)
    return (unsigned short)(u >> 16);
}
__device__ __forceinline__ float bf2f(unsigned short u) {
    uint32_t x = ((uint32_t)u) << 16;
    return __builtin_bit_cast(float, x);
}
// k-permutation baked into BOTH qn and sn fp8 layouts (dot-product invariant):
// swaps channel bits 3,4 — stays WITHIN each aligned 32-byte block, so the K=64
// MX MFMA (which pairs A/B byte-for-byte inside a lane's 32 contiguous k-bytes)
// is also invariant to it.
__device__ __forceinline__ int kperm(int c) {
    return (c & ~24) | ((c & 8) << 1) | ((c & 16) >> 1);
}

// CK-proven cast pattern: generic -> AS1/AS3 via uintptr
__device__ __forceinline__ void async_load16(const void* g, void* l) {
    auto gp = reinterpret_cast<const __attribute__((address_space(1))) uint32_t*>(
        reinterpret_cast<uintptr_t>(g));
    auto lp = reinterpret_cast<__attribute__((address_space(3))) uint32_t*>(
        reinterpret_cast<uintptr_t>(l));
    __builtin_amdgcn_global_load_lds(gp, lp, 16 /*bytes, literal*/, 0, 0);
}

// Branchless sorted-desc insert: r[i] = med3(v, r[i-1], r[i]) for i=14..1, then max.
__device__ __forceinline__ void ins15(float (&r)[15], float v) {
#pragma unroll
    for (int i = 14; i >= 1; --i) r[i] = __builtin_amdgcn_fmed3f(v, r[i - 1], r[i]);
    r[0] = fmaxf(r[0], v);
}

// ---------------- Phase A1: pool q (4x4 mean) + row-normalize -> fp8 (k-permuted) ----------------
__global__ __launch_bounds__(256) void pool_q_norm(const float* __restrict__ q,
                                                   char* __restrict__ qn) {
    int bb = blockIdx.x >> 3, h = blockIdx.x & 7;
    int t = threadIdx.x, lane = t & 63, wid = t >> 6;
    float vals[2][8];
    float ss[8] = {0, 0, 0, 0, 0, 0, 0, 0};
#pragma unroll
    for (int e = 0; e < 2; ++e) {
        int c = 2 * t + e;
        const float* base = q + ((size_t)(bb * 512 + c) * 1024 + 4 * h * 32);
#pragma unroll
        for (int w2 = 0; w2 < 8; ++w2) vals[e][w2] = 0.f;
#pragma unroll
        for (int i = 0; i < 4; ++i) {
            const float4* row = (const float4*)(base + i * 32);
#pragma unroll
            for (int w2 = 0; w2 < 8; ++w2) {
                float4 v = row[w2];
                vals[e][w2] += (v.x + v.y) + (v.z + v.w);
            }
        }
#pragma unroll
        for (int w2 = 0; w2 < 8; ++w2) {
            vals[e][w2] *= (1.f / 16.f);
            ss[w2] += vals[e][w2] * vals[e][w2];
        }
    }
    __shared__ float red[8][4];
#pragma unroll
    for (int k = 0; k < 8; ++k) {
        float v = ss[k];
#pragma unroll
        for (int o = 32; o > 0; o >>= 1) v += __shfl_xor(v, o, 64);
        if (lane == 0) red[k][wid] = v;
    }
    __syncthreads();
    int cp = kperm(2 * t);
#pragma unroll
    for (int w2 = 0; w2 < 8; ++w2) {
        float inv = rsqrtf(red[w2][0] + red[w2][1] + red[w2][2] + red[w2][3]);
        int p = __builtin_amdgcn_cvt_pk_fp8_f32(vals[0][w2] * inv, vals[1][w2] * inv, 0, false);
        *(unsigned short*)(qn + (size_t)(bb * 64 + h * 8 + w2) * 512 + cp) = (unsigned short)(p & 0xffff);
    }
}

// ------- Phase A2: pool S at BOTH scales + row-normalize -> fp8 (k-permuted) -------
__global__ __launch_bounds__(256) void pool_s_norm(const float* __restrict__ S,
                                                   char* __restrict__ sn) {
    int bb = blockIdx.x >> 3, h2 = blockIdx.x & 7;
    int t = threadIdx.x, lane = t & 63, wid = t >> 6;
    __shared__ unsigned short tile[40 * 512];   // 40KB raw-bf16 values
    __shared__ float rowsum[40];
#pragma unroll
    for (int e = 0; e < 2; ++e) {
        int c = 2 * t + e;
        const float* base = S + ((size_t)(bb * 512 + c) * 1024 + 4 * h2 * 32);
        float s1v[2][16];
#pragma unroll
        for (int j = 0; j < 2; ++j) {
            const float4* r0 = (const float4*)(base + (2 * j) * 32);
            const float4* r1 = (const float4*)(base + (2 * j + 1) * 32);
#pragma unroll
            for (int f = 0; f < 8; ++f) {
                float4 a = r0[f], b2 = r1[f];
                s1v[j][2 * f]     = (a.x + a.y + b2.x + b2.y) * 0.25f;
                s1v[j][2 * f + 1] = (a.z + a.w + b2.z + b2.w) * 0.25f;
            }
        }
#pragma unroll
        for (int j = 0; j < 2; ++j)
#pragma unroll
            for (int w1 = 0; w1 < 16; ++w1)
                tile[(j * 16 + w1) * 512 + c] = f2bf(s1v[j][w1]);
#pragma unroll
        for (int w2 = 0; w2 < 8; ++w2) {
            float src = (s1v[0][2 * w2] + s1v[0][2 * w2 + 1] +
                         s1v[1][2 * w2] + s1v[1][2 * w2 + 1]) * 0.25f;
            tile[(32 + w2) * 512 + c] = f2bf(src);
        }
    }
    __syncthreads();
    // Row sums-of-squares: wave wid owns rows 4k+wid; 64 lanes x 8 bf16 per row.
#pragma unroll
    for (int k = 0; k < 10; ++k) {
        int row = 4 * k + wid;
        u32x4 d = *(const u32x4*)(&tile[row * 512 + lane * 8]);
        float s = 0.f;
#pragma unroll
        for (int j = 0; j < 4; ++j) {
            float x0 = bf2f((unsigned short)(d[j] & 0xffffu));
            float x1 = bf2f((unsigned short)(d[j] >> 16));
            s += x0 * x0 + x1 * x1;
        }
#pragma unroll
        for (int o = 32; o > 0; o >>= 1) s += __shfl_xor(s, o, 64);
        if (lane == 0) rowsum[row] = s;
    }
    __syncthreads();
    // Scale + fp8 cast + k-permuted coalesced 8B stores: 40 rows x 64 segs.
#pragma unroll
    for (int k = 0; k < 10; ++k) {
        int idx = t + 256 * k;
        int r = idx >> 6, seg = idx & 63;
        float inv = rsqrtf(rowsum[r]);
        const unsigned short* src = &tile[r * 512 + seg * 8];
        float x[8];
#pragma unroll
        for (int m = 0; m < 8; ++m) x[m] = bf2f(src[m]) * inv;
        unsigned int w0 = (unsigned int)__builtin_amdgcn_cvt_pk_fp8_f32(
            x[2], x[3], __builtin_amdgcn_cvt_pk_fp8_f32(x[0], x[1], 0, false), true);
        unsigned int w1 = (unsigned int)__builtin_amdgcn_cvt_pk_fp8_f32(
            x[6], x[7], __builtin_amdgcn_cvt_pk_fp8_f32(x[4], x[5], 0, false), true);
        int nseg = (seg & ~3) | ((seg & 1) << 1) | ((seg >> 1) & 1);   // swap k-bits 3,4
        int grow = (r < 32) ? (bb * 256 + (2 * h2 + (r >> 4)) * 16 + (r & 15))
                            : (32768 + bb * 64 + h2 * 8 + (r - 32));
        uint2 o2; o2.x = w0; o2.y = w1;
        *(uint2*)(sn + (size_t)grow * 512 + nseg * 8) = o2;
    }
}

// ---------------- Phase B: MX-scaled fp8 32x32x64 MFMA + pipelined top-15 ----------------
// Same schedule as R13 (triple-buffered LDS, 1 barrier/chunk, scan-in-MFMA-shadow,
// launch_bounds(256,2), XCD-pinned). CHANGE: inner product uses
// mfma_scale_f32_32x32x64_f8f6f4 with e8m0 scales = 127 (1.0) -> numerically
// identical math at ~2x the MFMA rate (R13's floor was the non-scaled fp8 pipe).
// Per chunk: 8 k-steps (K=64), each = 2 swizzled ds_read_b128 (true slot s is at
// swizzled slot s^rlo; reading addr (s^rlo) returns true slot s) + 1 MFMA +
// 2 ins15 of the previous chunk's summed acc.
__global__ __launch_bounds__(256, 2) void sim_topk(const char* __restrict__ qn,
                                                   const char* __restrict__ sn,
                                                   float* __restrict__ partial) {
    __shared__ char Bs[3][SC * 512];   // 3 x 16KB
    int id = blockIdx.x;
    int xcd = id & 7, j = id >> 3;     // j = 0..127
    int y = xcd * 4 + (j & 3);         // s-split 0..31, pinned to XCD
    int x = j >> 2;                    // q-tile 0..31
    int tid = threadIdx.x, lane = tid & 63, wid = tid >> 6;
    int rlo = lane & 31, hi = lane >> 5;
    int qbase = x * QT + wid * 32;
    int sbase = y * SPER;
    char* BsB = &Bs[0][0];

    // B fragments (q side, fp8): 32 q rows, K=512 as 8 groups of 64.
    // Lane's frag = 32 contiguous (permuted-layout) k-bytes: [kk*64 + hi*32, +32).
    i32x8 b[8];
    {
        const char* qp = qn + (size_t)(qbase + rlo) * 512 + hi * 32;
#pragma unroll
        for (int kk = 0; kk < 8; ++kk) b[kk] = *(const i32x8*)(qp + kk * 64);
    }

    float r0[15];
#pragma unroll
    for (int i = 0; i < 15; ++i) r0[i] = -2.0f;   // below min cosine

    auto stage = [&](int ch, int buf) {
#pragma unroll
        for (int ii = 0; ii < 4; ++ii) {
            int i = wid * 4 + ii;                 // wave-uniform instr idx, 2 rows each
            int row = 2 * i + hi;                 // 0..31
            size_t srcoff = (size_t)(sbase + ch * SC + row) * 512
                          + (size_t)((rlo ^ row) * 16);
            async_load16(sn + srcoff, BsB + buf * 16384 + i * 1024);
        }
    };

    // One K=64 step: 2 swizzled b128 reads -> i32x8 A-frag -> scaled MFMA.
    auto kstep = [&](const char* B0, int kk, f32x16& acc) {
        int s0 = kk * 4 + hi * 2;                 // 16B-slot of true bytes [kk*64+hi*32)
        u32x4 a0 = *(const u32x4*)(B0 + rlo * 512 + ((s0 ^ rlo) << 4));
        u32x4 a1 = *(const u32x4*)(B0 + rlo * 512 + (((s0 + 1) ^ rlo) << 4));
        i32x8 a = __builtin_shufflevector(__builtin_bit_cast(i32x4, a0),
                                          __builtin_bit_cast(i32x4, a1),
                                          0, 1, 2, 3, 4, 5, 6, 7);
        acc = __builtin_amdgcn_mfma_scale_f32_32x32x64_f8f6f4(
            a, b[kk], acc, 0 /*A=fp8*/, 0 /*B=fp8*/, 0, 127, 0, 127);
    };

    stage(0, 0);
    stage(1, 1);
    f32x16 sumP;                       // prev chunk's summed acc (scanned in shadow)
#pragma unroll
    for (int e = 0; e < 16; ++e) sumP[e] = -2.0f;
    int bufR = 0;   // buffer holding current chunk
    int bufS = 2;   // buffer to stage into
    int chS = 2;    // chunk to stage

    for (int it = 0; it < NCHUNK / 2; ++it) {
        // ---- even phase: MFMA chunk 2it; scan sumP (chunk 2it-1) ----
        asm volatile("s_waitcnt vmcnt(4)" ::: "memory");
        __builtin_amdgcn_s_barrier();
        stage(chS, bufS);
        chS = (chS + 1 == NCHUNK) ? 0 : chS + 1;
        bufS = (bufS + 1 == 3) ? 0 : bufS + 1;
#pragma unroll
        for (int kk = 0; kk < 8; ++kk) asm volatile("" : "+v"(b[kk]));
        const char* B0 = BsB + bufR * 16384;
        bufR = (bufR + 1 == 3) ? 0 : bufR + 1;
        f32x16 aE, aO;
#pragma unroll
        for (int e = 0; e < 16; ++e) { aE[e] = 0.f; aO[e] = 0.f; }
#pragma unroll
        for (int kk = 0; kk < 4; ++kk) {
            kstep(B0, 2 * kk, aE);
            kstep(B0, 2 * kk + 1, aO);
            ins15(r0, sumP[4 * kk + 0]);       // prev-chunk scan in MFMA shadow
            ins15(r0, sumP[4 * kk + 1]);
            ins15(r0, sumP[4 * kk + 2]);
            ins15(r0, sumP[4 * kk + 3]);
        }
        f32x16 sumA;
#pragma unroll
        for (int e = 0; e < 16; ++e) sumA[e] = aE[e] + aO[e];

        // ---- odd phase: MFMA chunk 2it+1; scan sumA (chunk 2it) ----
        asm volatile("s_waitcnt vmcnt(4)" ::: "memory");
        __builtin_amdgcn_s_barrier();
        stage(chS, bufS);
        chS = (chS + 1 == NCHUNK) ? 0 : chS + 1;
        bufS = (bufS + 1 == 3) ? 0 : bufS + 1;
        const char* B1 = BsB + bufR * 16384;
        bufR = (bufR + 1 == 3) ? 0 : bufR + 1;
        f32x16 bE, bO;
#pragma unroll
        for (int e = 0; e < 16; ++e) { bE[e] = 0.f; bO[e] = 0.f; }
#pragma unroll
        for (int kk = 0; kk < 4; ++kk) {
            kstep(B1, 2 * kk, bE);
            kstep(B1, 2 * kk + 1, bO);
            ins15(r0, sumA[4 * kk + 0]);       // chunk-2it scan in MFMA shadow
            ins15(r0, sumA[4 * kk + 1]);
            ins15(r0, sumA[4 * kk + 2]);
            ins15(r0, sumA[4 * kk + 3]);
        }
#pragma unroll
        for (int e = 0; e < 16; ++e) sumP[e] = bE[e] + bO[e];
    }
    // epilogue: scan the final chunk
#pragma unroll
    for (int e = 0; e < 16; ++e) ins15(r0, sumP[e]);

    // Emit: partial[qrow][split][sub][15], sub = hi (s-row half within chunk rows)
    int q0 = qbase + rlo;
    float* dst = partial + (((size_t)q0 * NSPLIT + y) * 2 + hi) * 15;
#pragma unroll
    for (int i = 0; i < 15; ++i) dst[i] = r0[i];
}

// ---------------- Final: merge 960 candidates/row -> top15 -> LSE/top4 loss ----------------
// Wave per row, 4 rows/block, no per-round barriers, one atomicAdd per block.
__global__ __launch_bounds__(256) void topk_loss(const float* __restrict__ partial,
                                                 float* __restrict__ accum) {
    int t = threadIdx.x, lane = t & 63, wid = t >> 6;
    int r = blockIdx.x * 4 + wid;
    const float* src = partial + (size_t)r * NCAND;
    float v[15];
#pragma unroll
    for (int i = 0; i < 15; ++i) v[i] = src[lane + 64 * i];
    float m0 = 0.f, sexp = 0.f, top4 = 0.f;
#pragma unroll
    for (int round = 0; round < 15; ++round) {
        float m = v[0];
        int mi = lane * 16;
#pragma unroll
        for (int i = 1; i < 15; ++i)
            if (v[i] > m) { m = v[i]; mi = lane * 16 + i; }
#pragma unroll
        for (int o = 32; o > 0; o >>= 1) {
            float om = __shfl_xor(m, o, 64);
            int oi = __shfl_xor(mi, o, 64);
            if (om > m || (om == m && oi < mi)) { m = om; mi = oi; }
        }
        int wl = mi >> 4, wi = mi & 15;
#pragma unroll
        for (int i = 0; i < 15; ++i)
            if (i == wi && wl == lane) v[i] = -1e30f;   // static-index clear
        if (round == 0) m0 = m;
        sexp += expf(m - m0);
        if (round < 4) top4 += m;
    }
    float loss = m0 + logf(sexp) - 0.25f * top4;
    __shared__ float red[4];
    if (lane == 0) red[wid] = loss;
    __syncthreads();
    if (t == 0) atomicAdd(accum, red[0] + red[1] + red[2] + red[3]);
}

__global__ void finalize_out(const float* __restrict__ accum, float* __restrict__ out) {
    out[0] = accum[0] * (1.0f / (float)NQ);
}

// ---------------- Launch ----------------
extern "C" void kernel_launch(void* const* d_in, const int* in_sizes, int n_in,
                              void* d_out, int out_size, void* d_ws, size_t ws_size,
                              hipStream_t stream) {
    (void)in_sizes; (void)n_in; (void)out_size; (void)ws_size;
    const float* q = (const float*)d_in[0];
    const float* S = (const float*)d_in[1];
    char* ws = (char*)d_ws;
    char* qn = ws;                                                   //  2,097,152 B
    char* sn = ws + 2097152;                                         // 20,971,520 B
    float* partial = (float*)(ws + 2097152 + 20971520);              // 15,728,640 B
    float* accum   = (float*)(ws + 2097152 + 20971520 + 15728640);   // 4 B

    hipMemsetAsync(accum, 0, 4, stream);
    pool_q_norm<<<512, 256, 0, stream>>>(q, qn);
    pool_s_norm<<<1024, 256, 0, stream>>>(S, sn);
    sim_topk<<<1024, 256, 0, stream>>>(qn, sn, partial);
    topk_loss<<<NQ / 4, 256, 0, stream>>>(partial, accum);
    finalize_out<<<1, 1, 0, stream>>>(accum, (float*)d_out);
}

// Round 15
// 264.171 us; speedup vs baseline: 4.4146x; 1.0172x over previous
//
#include <hip/hip_runtime.h>
#include <hip/hip_bf16.h>
#include <stdint.h>

// Problem geometry (fixed by reference)
#define NQ 4096      // 64*8*8 query rows
#define NS 40960     // 32768 (s1) + 8192 (s_src)
#define CDIM 512
#define QT 256       // q rows per block: 4 waves x 64 q (2 groups of 32)
#define SC 32        // s rows per chunk
#define NSPLIT 32    // s-dimension splits
#define SPER (NS / NSPLIT)   // 1280
#define NCHUNK (SPER / SC)   // 40
#define NCAND 960    // per-row candidates: 32 splits * 2 lane-halves * 15

typedef float f32x16 __attribute__((ext_vector_type(16)));
typedef unsigned int u32x4 __attribute__((ext_vector_type(4)));
typedef int i32x4 __attribute__((ext_vector_type(4)));
typedef int i32x8 __attribute__((ext_vector_type(8)));

__device__ __forceinline__ unsigned short f2bf(float f) {
    uint32_t u = __builtin_bit_cast(uint32_t, f);
    u += 0x7fffu + ((u >> 16) & 1u);   // RNE (finite values only here)
    return (unsigned short)(u >> 16);
}
__device__ __forceinline__ float bf2f(unsigned short u) {
    uint32_t x = ((uint32_t)u) << 16;
    return __builtin_bit_cast(float, x);
}

// fp4 e2m1 encode of y (already pre-scaled by 16; e8m0 operand scale 2^-4 undoes it).
// Representable magnitudes {0,.5,1,1.5,2,3,4,6}; midpoint thresholds; sign bit3.
__device__ __forceinline__ unsigned fp4enc(float y) {
    float m = fabsf(y);
    unsigned c = (m < 0.25f) ? 0u : (m < 0.75f) ? 1u : (m < 1.25f) ? 2u
               : (m < 1.75f) ? 3u : (m < 2.5f)  ? 4u : (m < 3.5f)  ? 5u
               : (m < 5.0f)  ? 6u : 7u;
    return c | ((__builtin_bit_cast(unsigned, y) >> 28) & 8u);
}

// CK-proven cast pattern: generic -> AS1/AS3 via uintptr
__device__ __forceinline__ void async_load16(const void* g, void* l) {
    auto gp = reinterpret_cast<const __attribute__((address_space(1))) uint32_t*>(
        reinterpret_cast<uintptr_t>(g));
    auto lp = reinterpret_cast<__attribute__((address_space(3))) uint32_t*>(
        reinterpret_cast<uintptr_t>(l));
    __builtin_amdgcn_global_load_lds(gp, lp, 16 /*bytes, literal*/, 0, 0);
}

// Branchless sorted-desc insert: r[i] = med3(v, r[i-1], r[i]) for i=14..1, then max.
__device__ __forceinline__ void ins15(float (&r)[15], float v) {
#pragma unroll
    for (int i = 14; i >= 1; --i) r[i] = __builtin_amdgcn_fmed3f(v, r[i - 1], r[i]);
    r[0] = fmaxf(r[0], v);
}

// ---------------- Phase A1: pool q (4x4 mean) + row-normalize -> fp4 ----------------
// Thread t owns channels 2t (low nibble), 2t+1 (high nibble) -> byte t of the 256B row.
__global__ __launch_bounds__(256) void pool_q_norm(const float* __restrict__ q,
                                                   unsigned char* __restrict__ qn) {
    int bb = blockIdx.x >> 3, h = blockIdx.x & 7;
    int t = threadIdx.x, lane = t & 63, wid = t >> 6;
    float vals[2][8];
    float ss[8] = {0, 0, 0, 0, 0, 0, 0, 0};
#pragma unroll
    for (int e = 0; e < 2; ++e) {
        int c = 2 * t + e;
        const float* base = q + ((size_t)(bb * 512 + c) * 1024 + 4 * h * 32);
#pragma unroll
        for (int w2 = 0; w2 < 8; ++w2) vals[e][w2] = 0.f;
#pragma unroll
        for (int i = 0; i < 4; ++i) {
            const float4* row = (const float4*)(base + i * 32);
#pragma unroll
            for (int w2 = 0; w2 < 8; ++w2) {
                float4 v = row[w2];
                vals[e][w2] += (v.x + v.y) + (v.z + v.w);
            }
        }
#pragma unroll
        for (int w2 = 0; w2 < 8; ++w2) {
            vals[e][w2] *= (1.f / 16.f);
            ss[w2] += vals[e][w2] * vals[e][w2];
        }
    }
    __shared__ float red[8][4];
#pragma unroll
    for (int k = 0; k < 8; ++k) {
        float v = ss[k];
#pragma unroll
        for (int o = 32; o > 0; o >>= 1) v += __shfl_xor(v, o, 64);
        if (lane == 0) red[k][wid] = v;
    }
    __syncthreads();
#pragma unroll
    for (int w2 = 0; w2 < 8; ++w2) {
        float inv16 = rsqrtf(red[w2][0] + red[w2][1] + red[w2][2] + red[w2][3]) * 16.f;
        unsigned e0 = fp4enc(vals[0][w2] * inv16);
        unsigned e1 = fp4enc(vals[1][w2] * inv16);
        qn[(size_t)(bb * 64 + h * 8 + w2) * 256 + t] = (unsigned char)(e0 | (e1 << 4));
    }
}

// ------- Phase A2: pool S at BOTH scales + row-normalize -> fp4 -------
__global__ __launch_bounds__(256) void pool_s_norm(const float* __restrict__ S,
                                                   unsigned char* __restrict__ sn) {
    int bb = blockIdx.x >> 3, h2 = blockIdx.x & 7;
    int t = threadIdx.x, lane = t & 63, wid = t >> 6;
    __shared__ unsigned short tile[40 * 512];   // 40KB raw-bf16 values
    __shared__ float rowsum[40];
#pragma unroll
    for (int e = 0; e < 2; ++e) {
        int c = 2 * t + e;
        const float* base = S + ((size_t)(bb * 512 + c) * 1024 + 4 * h2 * 32);
        float s1v[2][16];
#pragma unroll
        for (int j = 0; j < 2; ++j) {
            const float4* r0 = (const float4*)(base + (2 * j) * 32);
            const float4* r1 = (const float4*)(base + (2 * j + 1) * 32);
#pragma unroll
            for (int f = 0; f < 8; ++f) {
                float4 a = r0[f], b2 = r1[f];
                s1v[j][2 * f]     = (a.x + a.y + b2.x + b2.y) * 0.25f;
                s1v[j][2 * f + 1] = (a.z + a.w + b2.z + b2.w) * 0.25f;
            }
        }
#pragma unroll
        for (int j = 0; j < 2; ++j)
#pragma unroll
            for (int w1 = 0; w1 < 16; ++w1)
                tile[(j * 16 + w1) * 512 + c] = f2bf(s1v[j][w1]);
#pragma unroll
        for (int w2 = 0; w2 < 8; ++w2) {
            float src = (s1v[0][2 * w2] + s1v[0][2 * w2 + 1] +
                         s1v[1][2 * w2] + s1v[1][2 * w2 + 1]) * 0.25f;
            tile[(32 + w2) * 512 + c] = f2bf(src);
        }
    }
    __syncthreads();
    // Row sums-of-squares: wave wid owns rows 4k+wid; 64 lanes x 8 bf16 per row.
#pragma unroll
    for (int k = 0; k < 10; ++k) {
        int row = 4 * k + wid;
        u32x4 d = *(const u32x4*)(&tile[row * 512 + lane * 8]);
        float s = 0.f;
#pragma unroll
        for (int j = 0; j < 4; ++j) {
            float x0 = bf2f((unsigned short)(d[j] & 0xffffu));
            float x1 = bf2f((unsigned short)(d[j] >> 16));
            s += x0 * x0 + x1 * x1;
        }
#pragma unroll
        for (int o = 32; o > 0; o >>= 1) s += __shfl_xor(s, o, 64);
        if (lane == 0) rowsum[row] = s;
    }
    __syncthreads();
    // Scale + fp4 cast + coalesced 4B stores: 40 rows x 64 4B-units = 2560 units.
#pragma unroll
    for (int k = 0; k < 10; ++k) {
        int idx = t + 256 * k;
        int r = idx >> 6, seg = idx & 63;      // seg of 8 channels -> 4 bytes
        float inv16 = rsqrtf(rowsum[r]) * 16.f;
        const unsigned short* src = &tile[r * 512 + seg * 8];
        unsigned out = 0;
#pragma unroll
        for (int m = 0; m < 8; ++m)
            out |= fp4enc(bf2f(src[m]) * inv16) << (4 * m);
        int grow = (r < 32) ? (bb * 256 + (2 * h2 + (r >> 4)) * 16 + (r & 15))
                            : (32768 + bb * 64 + h2 * 8 + (r - 32));
        *(unsigned*)(sn + (size_t)grow * 256 + seg * 4) = out;
    }
}

// ---------------- Phase B: MX-fp4 32x32x64 MFMA + pipelined top-15 ----------------
// 512 blocks x 256 threads (4 waves x 64 q = 256-q tile), launch_bounds(256,2),
// 2 blocks/CU, exactly 1 round. XCD-pinned splits (xcd=id&7).
// fp4 row = 256B. Chunk = 32 s-rows = 8KB, TRIPLE-buffered (24KB), 1 barrier/chunk.
// Each LDS A-read (16B, ds_read_b128) feeds TWO MFMAs (q-groups b[0],b[1]) ->
// LDS traffic halved vs 32q; fp4 halves bytes again. b[2][8] u32x4 = 64 VGPR.
// Scales: e8m0 123 = 2^-4 per operand (data pre-scaled x16); 0x7B7B7B7B so every
// potential scale-block byte is 123. fmt cbsz=blgp=4 (E2M1).
// Scan of prev chunk (4 ins15/kstep) sits in the MFMA+LDS shadow (R13 pipeline).
__global__ __launch_bounds__(256, 2) void sim_topk(const unsigned char* __restrict__ qn,
                                                   const unsigned char* __restrict__ sn,
                                                   float* __restrict__ partial) {
    __shared__ char Bs[3][SC * 256];   // 3 x 8KB
    int id = blockIdx.x;
    int xcd = id & 7, j = id >> 3;     // j = 0..63
    int y = xcd * 4 + (j & 3);         // s-split 0..31, pinned to XCD
    int x = j >> 2;                    // q-tile 0..15
    int tid = threadIdx.x, lane = tid & 63, wid = tid >> 6;
    int rlo = lane & 31, hi = lane >> 5;
    int qbase = x * QT + wid * 64;
    int sbase = y * SPER;
    char* BsB = &Bs[0][0];

    // B fragments (q side, fp4): 2 groups x 32 q rows. Lane's kstep-kk frag =
    // channels [kk*64 + hi*32, +32) = 16B at qp + kk*32 + hi*16.
    u32x4 b[2][8];
#pragma unroll
    for (int g = 0; g < 2; ++g) {
        const unsigned char* qp = qn + (size_t)(qbase + g * 32 + rlo) * 256 + hi * 16;
#pragma unroll
        for (int kk = 0; kk < 8; ++kk) b[g][kk] = *(const u32x4*)(qp + kk * 32);
    }

    float r0[15], r1[15];
#pragma unroll
    for (int i = 0; i < 15; ++i) { r0[i] = -2.0f; r1[i] = -2.0f; }

    // Stage one 8KB chunk: 8 wave-instrs (2/wave), slot g = wavebase+lane,
    // row = g>>4, slot-in-row s = g&15, source pre-swizzled by (row&15).
    auto stage = [&](int ch, int buf) {
#pragma unroll
        for (int ii = 0; ii < 2; ++ii) {
            int g = (wid * 2 + ii) * 64 + lane;
            int row = g >> 4, s = g & 15;
            size_t srcoff = (size_t)(sbase + ch * SC + row) * 256
                          + (size_t)((s ^ (row & 15)) << 4);
            async_load16(sn + srcoff, BsB + buf * 8192 + (g << 4));
        }
    };

    // One K=64 kstep for both q-groups: 1 swizzled b128 A-read -> 2 scaled MFMAs.
    auto kstep = [&](const char* B0, int kk, f32x16& acc0, f32x16& acc1) {
        int s0 = kk * 2 + hi;
        u32x4 a4 = *(const u32x4*)(B0 + rlo * 256 + ((s0 ^ (rlo & 15)) << 4));
        i32x4 ai = __builtin_bit_cast(i32x4, a4);
        i32x8 a = __builtin_shufflevector(ai, (i32x4){0, 0, 0, 0}, 0, 1, 2, 3, 4, 5, 6, 7);
        i32x8 b0 = __builtin_shufflevector(__builtin_bit_cast(i32x4, b[0][kk]),
                                           (i32x4){0, 0, 0, 0}, 0, 1, 2, 3, 4, 5, 6, 7);
        i32x8 b1 = __builtin_shufflevector(__builtin_bit_cast(i32x4, b[1][kk]),
                                           (i32x4){0, 0, 0, 0}, 0, 1, 2, 3, 4, 5, 6, 7);
        acc0 = __builtin_amdgcn_mfma_scale_f32_32x32x64_f8f6f4(
            a, b0, acc0, 4, 4, 0, 0x7B7B7B7B, 0, 0x7B7B7B7B);
        acc1 = __builtin_amdgcn_mfma_scale_f32_32x32x64_f8f6f4(
            a, b1, acc1, 4, 4, 0, 0x7B7B7B7B, 0, 0x7B7B7B7B);
    };

    stage(0, 0);
    stage(1, 1);
    f32x16 cA0, cA1, pB0, pB1;         // current / previous chunk accs (ping-pong)
#pragma unroll
    for (int e = 0; e < 16; ++e) { pB0[e] = -2.0f; pB1[e] = -2.0f; }
    int bufR = 0, bufS = 2, chS = 2;

    for (int it = 0; it < NCHUNK / 2; ++it) {
        // ---- even phase: compute chunk 2it -> cA; scan pB (chunk 2it-1) ----
        asm volatile("s_waitcnt vmcnt(2)" ::: "memory");   // chunk-2it loads landed
        __builtin_amdgcn_s_barrier();
        stage(chS, bufS);
        chS = (chS + 1 == NCHUNK) ? 0 : chS + 1;
        bufS = (bufS + 1 == 3) ? 0 : bufS + 1;
#pragma unroll
        for (int g = 0; g < 2; ++g)
#pragma unroll
            for (int kk = 0; kk < 8; ++kk) asm volatile("" : "+v"(b[g][kk]));
        const char* B0 = BsB + bufR * 8192;
        bufR = (bufR + 1 == 3) ? 0 : bufR + 1;
#pragma unroll
        for (int e = 0; e < 16; ++e) { cA0[e] = 0.f; cA1[e] = 0.f; }
#pragma unroll
        for (int kk = 0; kk < 8; ++kk) {
            kstep(B0, kk, cA0, cA1);
            ins15(r0, pB0[2 * kk]);
            ins15(r0, pB0[2 * kk + 1]);
            ins15(r1, pB1[2 * kk]);
            ins15(r1, pB1[2 * kk + 1]);
        }

        // ---- odd phase: compute chunk 2it+1 -> pB; scan cA (chunk 2it) ----
        asm volatile("s_waitcnt vmcnt(2)" ::: "memory");
        __builtin_amdgcn_s_barrier();
        stage(chS, bufS);
        chS = (chS + 1 == NCHUNK) ? 0 : chS + 1;
        bufS = (bufS + 1 == 3) ? 0 : bufS + 1;
        const char* B1 = BsB + bufR * 8192;
        bufR = (bufR + 1 == 3) ? 0 : bufR + 1;
#pragma unroll
        for (int e = 0; e < 16; ++e) { pB0[e] = 0.f; pB1[e] = 0.f; }
#pragma unroll
        for (int kk = 0; kk < 8; ++kk) {
            kstep(B1, kk, pB0, pB1);
            ins15(r0, cA0[2 * kk]);
            ins15(r0, cA0[2 * kk + 1]);
            ins15(r1, cA1[2 * kk]);
            ins15(r1, cA1[2 * kk + 1]);
        }
    }
    // epilogue: scan the final chunk (39)
#pragma unroll
    for (int e = 0; e < 16; ++e) { ins15(r0, pB0[e]); ins15(r1, pB1[e]); }

    // Emit: partial[qrow][split][sub][15], sub = hi
    int q0 = qbase + rlo;
    float* dst0 = partial + (((size_t)q0 * NSPLIT + y) * 2 + hi) * 15;
    float* dst1 = partial + (((size_t)(q0 + 32) * NSPLIT + y) * 2 + hi) * 15;
#pragma unroll
    for (int i = 0; i < 15; ++i) { dst0[i] = r0[i]; dst1[i] = r1[i]; }
}

// ---------------- Final: merge 960 candidates/row -> top15 -> LSE/top4 loss ----------------
// Wave per row, 4 rows/block, no per-round barriers, one atomicAdd per block.
__global__ __launch_bounds__(256) void topk_loss(const float* __restrict__ partial,
                                                 float* __restrict__ accum) {
    int t = threadIdx.x, lane = t & 63, wid = t >> 6;
    int r = blockIdx.x * 4 + wid;
    const float* src = partial + (size_t)r * NCAND;
    float v[15];
#pragma unroll
    for (int i = 0; i < 15; ++i) v[i] = src[lane + 64 * i];
    float m0 = 0.f, sexp = 0.f, top4 = 0.f;
#pragma unroll
    for (int round = 0; round < 15; ++round) {
        float m = v[0];
        int mi = lane * 16;
#pragma unroll
        for (int i = 1; i < 15; ++i)
            if (v[i] > m) { m = v[i]; mi = lane * 16 + i; }
#pragma unroll
        for (int o = 32; o > 0; o >>= 1) {
            float om = __shfl_xor(m, o, 64);
            int oi = __shfl_xor(mi, o, 64);
            if (om > m || (om == m && oi < mi)) { m = om; mi = oi; }
        }
        int wl = mi >> 4, wi = mi & 15;
#pragma unroll
        for (int i = 0; i < 15; ++i)
            if (i == wi && wl == lane) v[i] = -1e30f;   // static-index clear
        if (round == 0) m0 = m;
        sexp += expf(m - m0);
        if (round < 4) top4 += m;
    }
    float loss = m0 + logf(sexp) - 0.25f * top4;
    __shared__ float red[4];
    if (lane == 0) red[wid] = loss;
    __syncthreads();
    if (t == 0) atomicAdd(accum, red[0] + red[1] + red[2] + red[3]);
}

__global__ void finalize_out(const float* __restrict__ accum, float* __restrict__ out) {
    out[0] = accum[0] * (1.0f / (float)NQ);
}

// ---------------- Launch ----------------
extern "C" void kernel_launch(void* const* d_in, const int* in_sizes, int n_in,
                              void* d_out, int out_size, void* d_ws, size_t ws_size,
                              hipStream_t stream) {
    (void)in_sizes; (void)n_in; (void)out_size; (void)ws_size;
    const float* q = (const float*)d_in[0];
    const float* S = (const float*)d_in[1];
    char* ws = (char*)d_ws;
    unsigned char* qn = (unsigned char*)ws;                          //  1,048,576 B
    unsigned char* sn = (unsigned char*)(ws + 1048576);              // 10,485,760 B
    float* partial = (float*)(ws + 1048576 + 10485760);              // 15,728,640 B
    float* accum   = (float*)(ws + 1048576 + 10485760 + 15728640);   // 4 B

    hipMemsetAsync(accum, 0, 4, stream);
    pool_q_norm<<<512, 256, 0, stream>>>(q, qn);
    pool_s_norm<<<1024, 256, 0, stream>>>(S, sn);
    sim_topk<<<512, 256, 0, stream>>>(qn, sn, partial);
    topk_loss<<<NQ / 4, 256, 0, stream>>>(partial, accum);
    finalize_out<<<1, 1, 0, stream>>>(accum, (float*)d_out);
}